// Round 21
// baseline (81.201 us; speedup 1.0000x reference)
//
#include <hip/hip_runtime.h>
#include <stdint.h>

typedef _Float16 half_t;
typedef __attribute__((ext_vector_type(8))) _Float16 f16x8;
typedef __attribute__((ext_vector_type(4))) _Float16 f16x4;
typedef __attribute__((ext_vector_type(2))) __fp16 fp16x2;
typedef __attribute__((ext_vector_type(4))) float f32x4;
typedef __attribute__((ext_vector_type(16))) float f32x16;
typedef __attribute__((ext_vector_type(4))) uint32_t u32x4;
typedef __attribute__((ext_vector_type(2))) int i32x2;

#define DEVI __device__ __forceinline__

static constexpr int Bn = 4, Cc = 256, Nn = 4096, PD = 32;
static constexpr float L2E = 1.44269504089f;
static constexpr float THR = 11.5416f;          // 8 * log2(e)

// persistent f16 intermediates (module-scope device memory; fully rewritten every call)
__device__ half_t g_Q[(size_t)Bn * Nn * PD];   // [b][n][d], PRE-SCALED by log2(e)
__device__ half_t g_K[(size_t)Bn * Nn * PD];   // [b][n][d]  (= k^T)
__device__ half_t g_V[(size_t)Bn * Cc * Nn];   // [b][e][n]

DEVI f16x8 cvt8(float4 a, float4 b) {
    f16x8 r;
    r[0] = (_Float16)a.x; r[1] = (_Float16)a.y; r[2] = (_Float16)a.z; r[3] = (_Float16)a.w;
    r[4] = (_Float16)b.x; r[5] = (_Float16)b.y; r[6] = (_Float16)b.z; r[7] = (_Float16)b.w;
    return r;
}

DEVI uint32_t pkrtz(float a, float b) {
    fp16x2 h = __builtin_amdgcn_cvt_pkrtz(a, b);
    return __builtin_bit_cast(uint32_t, h);
}

DEVI float asf(int u) { return __builtin_bit_cast(float, u); }
DEVI int   asi(float f) { return __builtin_bit_cast(int, f); }

DEVI i32x2 pl32swap(int a, int b) {
    return __builtin_amdgcn_permlane32_swap(a, b, false, false);
}

// async global->LDS, 16B per lane; LDS dest is wave-uniform base + lane*16
DEVI void gll16(const void* g, void* l) {
    auto gp = (const __attribute__((address_space(1))) uint32_t*)(uintptr_t)g;
    auto lp = (__attribute__((address_space(3))) uint32_t*)(uintptr_t)l;
    __builtin_amdgcn_global_load_lds(gp, lp, 16, 0, 0);
}

// ---------------- projection (64-wide grid-256; Q scaled by L2E) ----------------
__global__ __launch_bounds__(256, 1) void proj_kernel(
    const float* __restrict__ x,
    const float* __restrict__ Wq, const float* __restrict__ bq,
    const float* __restrict__ Wk, const float* __restrict__ bk,
    const float* __restrict__ Wv, const float* __restrict__ bv)
{
    __shared__ __align__(16) half_t xt[64 * 40];   // [n][c] tile, pad 32->40

    const int b    = blockIdx.x >> 6;
    const int n0   = (blockIdx.x & 63) * 64;
    const int t    = threadIdx.x;
    const int w    = t >> 6;
    const int lane = t & 63;
    const int l15  = lane & 15, g = lane >> 4;

    f32x4 qk_acc[4] = {};
    f32x4 v_acc[4][4] = {};

    const float* wrow_qk = (w < 2) ? (Wq + (size_t)(16 * w + l15) * Cc)
                                   : (Wk + (size_t)(16 * (w - 2) + l15) * Cc);

    for (int cs = 0; cs < 8; ++cs) {
        const int c0 = cs * 32;
        {
            const int nl = t & 63;
            const int cg = t >> 6;
            const float* xp = x + ((size_t)(b * Cc + c0 + cg * 8)) * Nn + n0 + nl;
            float f[8];
#pragma unroll
            for (int q = 0; q < 8; ++q) f[q] = xp[(size_t)q * Nn];
            f16x4 h0, h1;
#pragma unroll
            for (int q = 0; q < 4; ++q) { h0[q] = (_Float16)f[q]; h1[q] = (_Float16)f[q + 4]; }
            *(f16x4*)&xt[nl * 40 + cg * 8]     = h0;
            *(f16x4*)&xt[nl * 40 + cg * 8 + 4] = h1;
        }
        __syncthreads();

        f16x8 xf[4];
#pragma unroll
        for (int nf = 0; nf < 4; ++nf)
            xf[nf] = *(const f16x8*)&xt[(nf * 16 + l15) * 40 + g * 8];

        {
            const float* wp = wrow_qk + c0 + g * 8;
            const f16x8 af = cvt8(*(const float4*)wp, *(const float4*)(wp + 4));
#pragma unroll
            for (int nt = 0; nt < 4; ++nt)
                qk_acc[nt] = __builtin_amdgcn_mfma_f32_16x16x32_f16(af, xf[nt], qk_acc[nt], 0, 0, 0);
        }
#pragma unroll
        for (int et = 0; et < 4; ++et) {
            const int e = (w * 4 + et) * 16 + l15;
            const float* wp = Wv + (size_t)e * Cc + c0 + g * 8;
            const f16x8 wf = cvt8(*(const float4*)wp, *(const float4*)(wp + 4));
#pragma unroll
            for (int nf = 0; nf < 4; ++nf)
                v_acc[et][nf] = __builtin_amdgcn_mfma_f32_16x16x32_f16(xf[nf], wf, v_acc[et][nf], 0, 0, 0);
        }
        __syncthreads();
    }

    {
        const float* bias = (w < 2) ? bq : bk;
        const float scl   = (w < 2) ? L2E : 1.f;   // Q pre-scaled into log2 units
        const int dbase = 16 * (w & 1) + 4 * g;
        float bb[4];
#pragma unroll
        for (int r = 0; r < 4; ++r) bb[r] = bias[dbase + r];
        half_t* dst = (w < 2) ? g_Q : g_K;
#pragma unroll
        for (int nt = 0; nt < 4; ++nt) {
            const int n = n0 + nt * 16 + l15;
            f16x4 h;
#pragma unroll
            for (int r = 0; r < 4; ++r) h[r] = (_Float16)((qk_acc[nt][r] + bb[r]) * scl);
            *(f16x4*)&dst[((size_t)b * Nn + n) * PD + dbase] = h;
        }
    }
#pragma unroll
    for (int et = 0; et < 4; ++et) {
        const int e = (w * 4 + et) * 16 + l15;
        const float bve = bv[e];
#pragma unroll
        for (int nf = 0; nf < 4; ++nf) {
            const int n = n0 + nf * 16 + 4 * g;
            f16x4 h;
#pragma unroll
            for (int r = 0; r < 4; ++r) h[r] = (_Float16)(v_acc[et][nf][r] + bve);
            *(f16x4*)&g_V[((size_t)b * Cc + e) * Nn + n] = h;
        }
    }
}

// ------- fused flash attention + residual (v20 = v16 + 4-bit LDS swizzle) ----------
// Grid 256 = 1 block/CU; block = 512 thr = 8 waves (mh = w>>2, kk = w&3); R=1.
// SINGLE change vs v16/v19: the V LDS involution widens from ^(row&7) to
// ^(row&15) on BOTH the gll source and the ds_read offsets.  The old 3-bit XOR
// spread 32 reading lanes over only 8 chunk groups -> 4-way bank conflict
// (1.58x, m136); 4-bit uses all 16 chunks -> 2-way, which is free (1.02x).
__global__ __launch_bounds__(512, 2) void attn_kernel(
    const float* __restrict__ x, const float* __restrict__ gamma_p, float* __restrict__ out)
{
    __shared__ __align__(16) half_t V_lds[2][256 * 128];  // 128KB
    __shared__ float mx[2][4][32];                        // [mh][kk][m-local]
    __shared__ float lx[2][4][32];

    const int blk = blockIdx.x;
    const int grp = blk & 7;                 // XCD id; b = grp>>1 (V slice L2-local)
    const int b   = grp >> 1;
    const int mt  = ((blk >> 3) << 1) | (grp & 1);   // 0..63

    const int t    = threadIdx.x;
    const int w    = t >> 6;                 // 0..7
    const int lane = t & 63;
    const int l31  = lane & 31;
    const int hi   = lane >> 5;
    const int kk   = w & 3;                  // n-quarter of 128-tile
    const int mh   = w >> 2;                 // m-half of 64m
    const int mrow0 = mt * 64 + mh * 32;

    const half_t* Kb  = g_K + (size_t)b * Nn * PD;
    const half_t* Vbg = g_V + (size_t)b * Cc * Nn;

    // Q frags: rows m = mrow0 + l31; d-slices hi*8 / 16+hi*8 (log2-prescaled)
    const half_t* qp = g_Q + ((size_t)b * Nn + mrow0 + l31) * PD + hi * 8;
    const f16x8 q0 = *(const f16x8*)qp;
    const f16x8 q1 = *(const f16x8*)(qp + 16);

    // V gll source (per-lane): e-row vr = w*4 + (lane>>4) (+32 per round),
    // chunk pc = lane&15, source col pre-swizzled with the 4-BIT involution:
    // n-chunk = pc ^ (vr & 15)   (rr*32 ≡ 0 mod 16, so rr-invariant)
    const int vr = w * 4 + (lane >> 4);
    const half_t* vb = Vbg + (size_t)vr * Nn + (((lane & 15) ^ (vr & 15)) * 8);

    // PV V-read offsets: row el = et*32+l31 -> (el&15) = (l31&15); logical chunk
    // c = kk*4 + ks*2 + hi, physical = c ^ (l31 & 15)
    const int e15  = l31 & 15;
    const int off0 = (((kk * 4) + hi) ^ e15) * 8;
    const int off1 = (((kk * 4) + 2 + hi) ^ e15) * 8;

    f32x16 acc[8] = {};   // [et]: col e = et*32+l31, row m = mrow0+(r&3)+8*(r>>2)+4*hi
    float run_m = -1e30f, run_l = 0.f;
    const f32x16 zero16 = {};

    f32x16 s;             // current tile's S^T (log2 units)
    f16x8 kq0, kq1;       // K frags for NEXT tile

    // ---- prologue: QK(0) direct; gll V(0); prefetch K(1) ----
    {
        const half_t* kp0 = Kb + (size_t)(kk * 32 + l31) * PD + hi * 8;
        const f16x8 ka = *(const f16x8*)kp0;
        const f16x8 kb = *(const f16x8*)(kp0 + 16);
        s = __builtin_amdgcn_mfma_f32_32x32x16_f16(ka, q0, zero16, 0, 0, 0);
        s = __builtin_amdgcn_mfma_f32_32x32x16_f16(kb, q1, s, 0, 0, 0);
    }
#pragma unroll
    for (int rr = 0; rr < 8; ++rr)
        gll16(vb + (size_t)rr * 32 * Nn, &V_lds[0][rr * 4096 + w * 512]);
    __builtin_amdgcn_sched_barrier(0);
    const half_t* kp = Kb + (size_t)(128 + kk * 32 + l31) * PD + hi * 8;
    kq0 = *(const f16x8*)kp;
    kq1 = *(const f16x8*)(kp + 16);
    __builtin_amdgcn_sched_barrier(0);

    constexpr int NT = Nn / 128;
    for (int i = 0; i < NT; ++i) {
        const int buf = i & 1;
        const bool more = (i + 1 < NT);

        // counted drain: the 8 gll for tile i are the oldest; 2 K loads may stay.
        asm volatile("s_waitcnt vmcnt(2)" ::: "memory");
        __builtin_amdgcn_s_barrier();
        __builtin_amdgcn_sched_barrier(0);

        // ---- softmax in-register, log2-native (row m = l31) ----
        float tm = s[0];
#pragma unroll
        for (int r = 1; r < 16; ++r) tm = fmaxf(tm, s[r]);
        {
            const i32x2 rr = pl32swap(asi(tm), asi(tm));
            tm = fmaxf(asf(rr[0]), asf(rr[1]));
        }
        float alpha = 1.f;
        if (__any(tm > run_m + THR)) {
            const float nm = fmaxf(run_m, tm);
            alpha = __builtin_amdgcn_exp2f(run_m - nm);
            run_m = nm;
            float a16[16];
#pragma unroll
            for (int r = 0; r < 16; ++r)
                a16[r] = __shfl(alpha, (r & 3) + 8 * (r >> 2) + 4 * hi);
#pragma unroll
            for (int et = 0; et < 8; ++et)
#pragma unroll
                for (int r = 0; r < 16; ++r) acc[et][r] *= a16[r];
        }

        float p[16];
#pragma unroll
        for (int r = 0; r < 16; ++r)
            p[r] = __builtin_amdgcn_exp2f(s[r] - run_m);
        float rs = (((p[0] + p[1]) + (p[2] + p[3])) + ((p[4] + p[5]) + (p[6] + p[7])))
                 + (((p[8] + p[9]) + (p[10] + p[11])) + ((p[12] + p[13]) + (p[14] + p[15])));
        {
            const i32x2 rr = pl32swap(asi(rs), asi(rs));
            rs = asf(rr[0]) + asf(rr[1]);
        }
        run_l = run_l * alpha + rs;

        // ---- pack P into PV A-frags (v10-verified) ----
        f16x8 pa0, pa1;
        {
            const i32x2 r0 = pl32swap((int)pkrtz(p[0], p[1]), (int)pkrtz(p[4], p[5]));
            const i32x2 r1 = pl32swap((int)pkrtz(p[2], p[3]), (int)pkrtz(p[6], p[7]));
            u32x4 d0 = {(uint32_t)r0[0], (uint32_t)r1[0], (uint32_t)r0[1], (uint32_t)r1[1]};
            pa0 = __builtin_bit_cast(f16x8, d0);
            const i32x2 r2 = pl32swap((int)pkrtz(p[8], p[9]),   (int)pkrtz(p[12], p[13]));
            const i32x2 r3 = pl32swap((int)pkrtz(p[10], p[11]), (int)pkrtz(p[14], p[15]));
            u32x4 d1 = {(uint32_t)r2[0], (uint32_t)r3[0], (uint32_t)r2[1], (uint32_t)r3[1]};
            pa1 = __builtin_bit_cast(f16x8, d1);
        }

        // issue gll for tile i+1 into the other buffer
        if (more) {
#pragma unroll
            for (int rr = 0; rr < 8; ++rr)
                gll16(vb + 128 + (size_t)rr * 32 * Nn, &V_lds[buf ^ 1][rr * 4096 + w * 512]);
            vb += 128;
        }
        __builtin_amdgcn_sched_barrier(0);

        // ---- PV: 8 e-tiles x 2 k-steps over wave's 32n quarter ----
        __builtin_amdgcn_s_setprio(1);
#pragma unroll
        for (int et = 0; et < 8; ++et) {
            const int rowb = (et * 32 + l31) * 128;
            const f16x8 vf0 = *(const f16x8*)&V_lds[buf][rowb + off0];
            const f16x8 vf1 = *(const f16x8*)&V_lds[buf][rowb + off1];
            acc[et] = __builtin_amdgcn_mfma_f32_32x32x16_f16(pa0, vf0, acc[et], 0, 0, 0);
            acc[et] = __builtin_amdgcn_mfma_f32_32x32x16_f16(pa1, vf1, acc[et], 0, 0, 0);
        }
        __builtin_amdgcn_s_setprio(0);

        // ---- QK for tile i+1; prefetch K for i+2 (tail-wrapped) ----
        if (more) {
            s = __builtin_amdgcn_mfma_f32_32x32x16_f16(kq0, q0, zero16, 0, 0, 0);
            s = __builtin_amdgcn_mfma_f32_32x32x16_f16(kq1, q1, s, 0, 0, 0);
            kp += 128 * PD;
            if (i + 2 >= NT) kp = Kb + (size_t)(kk * 32 + l31) * PD + hi * 8;  // dummy
            kq0 = *(const f16x8*)kp;
            kq1 = *(const f16x8*)(kp + 16);
            __builtin_amdgcn_sched_barrier(0);
        }
    }

    // ---- epilogue: 4-way kk merge with exact exp2 correction (log2 units) ----
    if (lane < 32) { mx[mh][kk][l31] = run_m; lx[mh][kk][l31] = run_l; }
    __syncthreads();

    float sc16[16], li16[16];
    {
        const float m0 = mx[mh][0][l31], m1 = mx[mh][1][l31];
        const float m2 = mx[mh][2][l31], m3 = mx[mh][3][l31];
        const float M  = fmaxf(fmaxf(m0, m1), fmaxf(m2, m3));
        const float L  = lx[mh][0][l31] * __builtin_amdgcn_exp2f(m0 - M)
                       + lx[mh][1][l31] * __builtin_amdgcn_exp2f(m1 - M)
                       + lx[mh][2][l31] * __builtin_amdgcn_exp2f(m2 - M)
                       + lx[mh][3][l31] * __builtin_amdgcn_exp2f(m3 - M);
        const float ssf = __builtin_amdgcn_exp2f(run_m - M);
        const float inv = 1.0f / L;
#pragma unroll
        for (int r = 0; r < 16; ++r) {
            const int src = (r & 3) + 8 * (r >> 2) + 4 * hi;
            sc16[r] = __shfl(ssf, src);
            li16[r] = __shfl(inv, src);
        }
    }
    __syncthreads();   // all mx/lx reads done before mrg overwrites V_lds

    const float gm = gamma_p[0];
    float4* mrg = (float4*)&V_lds[0][0];   // [slot 0..31][q 0..3][lane 0..63]
#pragma unroll
    for (int h = 0; h < 2; ++h) {
#pragma unroll
        for (int j = 0; j < 4; ++j) {
            const int et = h * 4 + j;
#pragma unroll
            for (int q = 0; q < 4; ++q) {
                float4 v;
                v.x = acc[et][4 * q + 0] * sc16[4 * q + 0];
                v.y = acc[et][4 * q + 1] * sc16[4 * q + 1];
                v.z = acc[et][4 * q + 2] * sc16[4 * q + 2];
                v.w = acc[et][4 * q + 3] * sc16[4 * q + 3];
                mrg[((w * 4 + j) * 4 + q) * 64 + lane] = v;
            }
        }
        __syncthreads();
        {
            const int et = h * 4 + kk;
            const int e  = et * 32 + l31;
#pragma unroll
            for (int q = 0; q < 4; ++q) {
                float4 s0 = mrg[(((mh * 4 + 0) * 4 + kk) * 4 + q) * 64 + lane];
                float4 s1 = mrg[(((mh * 4 + 1) * 4 + kk) * 4 + q) * 64 + lane];
                float4 s2 = mrg[(((mh * 4 + 2) * 4 + kk) * 4 + q) * 64 + lane];
                float4 s3 = mrg[(((mh * 4 + 3) * 4 + kk) * 4 + q) * 64 + lane];
                const size_t idx = ((size_t)b * Cc + e) * Nn + mrow0 + 8 * q + 4 * hi;
                const float4 xin = *(const float4*)&x[idx];
                float4 o;
                o.x = gm * (s0.x + s1.x + s2.x + s3.x) * li16[4 * q + 0] + xin.x;
                o.y = gm * (s0.y + s1.y + s2.y + s3.y) * li16[4 * q + 1] + xin.y;
                o.z = gm * (s0.z + s1.z + s2.z + s3.z) * li16[4 * q + 2] + xin.z;
                o.w = gm * (s0.w + s1.w + s2.w + s3.w) * li16[4 * q + 3] + xin.w;
                *(float4*)&out[idx] = o;
            }
        }
        __syncthreads();
    }
}

extern "C" void kernel_launch(void* const* d_in, const int* in_sizes, int n_in,
                              void* d_out, int out_size, void* d_ws, size_t ws_size,
                              hipStream_t stream) {
    (void)in_sizes; (void)n_in; (void)out_size; (void)d_ws; (void)ws_size;
    const float* x  = (const float*)d_in[0];
    const float* Wq = (const float*)d_in[1];
    const float* bq = (const float*)d_in[2];
    const float* Wk = (const float*)d_in[3];
    const float* bk = (const float*)d_in[4];
    const float* Wv = (const float*)d_in[5];
    const float* bv = (const float*)d_in[6];
    const float* gm = (const float*)d_in[7];
    float* out = (float*)d_out;

    proj_kernel<<<256, 256, 0, stream>>>(x, Wq, bq, Wk, bk, Wv, bv);
    attn_kernel<<<256, 512, 0, stream>>>(x, gm, out);
}

// Round 22
// 80.709 us; speedup vs baseline: 1.0061x; 1.0061x over previous
//
#include <hip/hip_runtime.h>
#include <stdint.h>

typedef _Float16 half_t;
typedef __attribute__((ext_vector_type(8))) _Float16 f16x8;
typedef __attribute__((ext_vector_type(4))) _Float16 f16x4;
typedef __attribute__((ext_vector_type(2))) __fp16 fp16x2;
typedef __attribute__((ext_vector_type(4))) float f32x4;
typedef __attribute__((ext_vector_type(16))) float f32x16;
typedef __attribute__((ext_vector_type(4))) uint32_t u32x4;
typedef __attribute__((ext_vector_type(2))) int i32x2;

#define DEVI __device__ __forceinline__

static constexpr int Bn = 4, Cc = 256, Nn = 4096, PD = 32;
static constexpr float L2E = 1.44269504089f;
static constexpr float THR = 11.5416f;          // 8 * log2(e)

// persistent f16 intermediates (module-scope device memory; fully rewritten every call)
__device__ half_t g_Q[(size_t)Bn * Nn * PD];   // [b][n][d], PRE-SCALED by log2(e)
__device__ half_t g_K[(size_t)Bn * Nn * PD];   // [b][n][d]  (= k^T)
__device__ half_t g_V[(size_t)Bn * Cc * Nn];   // [b][e][n]

DEVI f16x8 cvt8(float4 a, float4 b) {
    f16x8 r;
    r[0] = (_Float16)a.x; r[1] = (_Float16)a.y; r[2] = (_Float16)a.z; r[3] = (_Float16)a.w;
    r[4] = (_Float16)b.x; r[5] = (_Float16)b.y; r[6] = (_Float16)b.z; r[7] = (_Float16)b.w;
    return r;
}

DEVI uint32_t pkrtz(float a, float b) {
    fp16x2 h = __builtin_amdgcn_cvt_pkrtz(a, b);
    return __builtin_bit_cast(uint32_t, h);
}

DEVI float asf(int u) { return __builtin_bit_cast(float, u); }
DEVI int   asi(float f) { return __builtin_bit_cast(int, f); }

DEVI i32x2 pl32swap(int a, int b) {
    return __builtin_amdgcn_permlane32_swap(a, b, false, false);
}

// async global->LDS, 16B per lane; LDS dest is wave-uniform base + lane*16
DEVI void gll16(const void* g, void* l) {
    auto gp = (const __attribute__((address_space(1))) uint32_t*)(uintptr_t)g;
    auto lp = (__attribute__((address_space(3))) uint32_t*)(uintptr_t)l;
    __builtin_amdgcn_global_load_lds(gp, lp, 16, 0, 0);
}

// ------------- projection v21: e-split, grid 512 = 4b x 64nt x 2eh ---------------
// Block = 256 thr / 4 waves, 64-n tile, but only a 128-e HALF of Wv (eh).
// Wv traffic unchanged (512 blk x 128KB = 64MB); x read 2x (L3-resident, cheap);
// per-CU MFMA work identical; TLP doubles: 2 blocks/CU = 8 waves/CU (was 4).
// QK (small: 4 MFMA/cs) computed by eh==0 blocks only.  Q pre-scaled by log2(e).
__global__ __launch_bounds__(256, 2) void proj_kernel(
    const float* __restrict__ x,
    const float* __restrict__ Wq, const float* __restrict__ bq,
    const float* __restrict__ Wk, const float* __restrict__ bk,
    const float* __restrict__ Wv, const float* __restrict__ bv)
{
    __shared__ __align__(16) half_t xt[64 * 40];   // [n][c] tile, pad 32->40

    const int blk = blockIdx.x;
    const int b   = blk >> 7;
    const int sub = blk & 127;
    const int n0  = (sub >> 1) * 64;
    const int eh  = sub & 1;
    const int e0  = eh * 128;

    const int t    = threadIdx.x;
    const int w    = t >> 6;
    const int lane = t & 63;
    const int l15  = lane & 15, g = lane >> 4;

    f32x4 qk_acc[4] = {};
    f32x4 v_acc[2][4] = {};                  // [et][nf], e-half only

    const float* wrow_qk = (w < 2) ? (Wq + (size_t)(16 * w + l15) * Cc)
                                   : (Wk + (size_t)(16 * (w - 2) + l15) * Cc);

    for (int cs = 0; cs < 8; ++cs) {
        const int c0 = cs * 32;
        {
            const int nl = t & 63;
            const int cg = t >> 6;
            const float* xp = x + ((size_t)(b * Cc + c0 + cg * 8)) * Nn + n0 + nl;
            float f[8];
#pragma unroll
            for (int q = 0; q < 8; ++q) f[q] = xp[(size_t)q * Nn];
            f16x4 h0, h1;
#pragma unroll
            for (int q = 0; q < 4; ++q) { h0[q] = (_Float16)f[q]; h1[q] = (_Float16)f[q + 4]; }
            *(f16x4*)&xt[nl * 40 + cg * 8]     = h0;
            *(f16x4*)&xt[nl * 40 + cg * 8 + 4] = h1;
        }
        __syncthreads();

        f16x8 xf[4];
#pragma unroll
        for (int nf = 0; nf < 4; ++nf)
            xf[nf] = *(const f16x8*)&xt[(nf * 16 + l15) * 40 + g * 8];

        if (eh == 0) {
            const float* wp = wrow_qk + c0 + g * 8;
            const f16x8 af = cvt8(*(const float4*)wp, *(const float4*)(wp + 4));
#pragma unroll
            for (int nt = 0; nt < 4; ++nt)
                qk_acc[nt] = __builtin_amdgcn_mfma_f32_16x16x32_f16(af, xf[nt], qk_acc[nt], 0, 0, 0);
        }
#pragma unroll
        for (int et = 0; et < 2; ++et) {
            const int e = e0 + w * 32 + et * 16 + l15;
            const float* wp = Wv + (size_t)e * Cc + c0 + g * 8;
            const f16x8 wf = cvt8(*(const float4*)wp, *(const float4*)(wp + 4));
#pragma unroll
            for (int nf = 0; nf < 4; ++nf)
                v_acc[et][nf] = __builtin_amdgcn_mfma_f32_16x16x32_f16(xf[nf], wf, v_acc[et][nf], 0, 0, 0);
        }
        __syncthreads();
    }

    if (eh == 0) {
        const float* bias = (w < 2) ? bq : bk;
        const float scl   = (w < 2) ? L2E : 1.f;   // Q pre-scaled into log2 units
        const int dbase = 16 * (w & 1) + 4 * g;
        float bb[4];
#pragma unroll
        for (int r = 0; r < 4; ++r) bb[r] = bias[dbase + r];
        half_t* dst = (w < 2) ? g_Q : g_K;
#pragma unroll
        for (int nt = 0; nt < 4; ++nt) {
            const int n = n0 + nt * 16 + l15;
            f16x4 h;
#pragma unroll
            for (int r = 0; r < 4; ++r) h[r] = (_Float16)((qk_acc[nt][r] + bb[r]) * scl);
            *(f16x4*)&dst[((size_t)b * Nn + n) * PD + dbase] = h;
        }
    }
#pragma unroll
    for (int et = 0; et < 2; ++et) {
        const int e = e0 + w * 32 + et * 16 + l15;
        const float bve = bv[e];
#pragma unroll
        for (int nf = 0; nf < 4; ++nf) {
            const int n = n0 + nf * 16 + 4 * g;
            f16x4 h;
#pragma unroll
            for (int r = 0; r < 4; ++r) h[r] = (_Float16)(v_acc[et][nf][r] + bve);
            *(f16x4*)&g_V[((size_t)b * Cc + e) * Nn + n] = h;
        }
    }
}

// ------- fused flash attention + residual (v20, UNCHANGED: best measured, 0 conflicts) --
// Grid 256 = 1 block/CU; block = 512 thr = 8 waves (mh = w>>2, kk = w&3); R=1.
// Double-buffered V [2][256e][128n] via gll (4-bit XOR pre-swizzled source);
// counted vmcnt(2) + 1 barrier/iter; in-register log2-native softmax; P packed
// to MFMA A-frags via cvt_pkrtz + permlane32_swap (no LDS); 18 MFMA/wave-iter.
__global__ __launch_bounds__(512, 2) void attn_kernel(
    const float* __restrict__ x, const float* __restrict__ gamma_p, float* __restrict__ out)
{
    __shared__ __align__(16) half_t V_lds[2][256 * 128];  // 128KB
    __shared__ float mx[2][4][32];                        // [mh][kk][m-local]
    __shared__ float lx[2][4][32];

    const int blk = blockIdx.x;
    const int grp = blk & 7;                 // XCD id; b = grp>>1 (V slice L2-local)
    const int b   = grp >> 1;
    const int mt  = ((blk >> 3) << 1) | (grp & 1);   // 0..63

    const int t    = threadIdx.x;
    const int w    = t >> 6;                 // 0..7
    const int lane = t & 63;
    const int l31  = lane & 31;
    const int hi   = lane >> 5;
    const int kk   = w & 3;                  // n-quarter of 128-tile
    const int mh   = w >> 2;                 // m-half of 64m
    const int mrow0 = mt * 64 + mh * 32;

    const half_t* Kb  = g_K + (size_t)b * Nn * PD;
    const half_t* Vbg = g_V + (size_t)b * Cc * Nn;

    // Q frags: rows m = mrow0 + l31; d-slices hi*8 / 16+hi*8 (log2-prescaled)
    const half_t* qp = g_Q + ((size_t)b * Nn + mrow0 + l31) * PD + hi * 8;
    const f16x8 q0 = *(const f16x8*)qp;
    const f16x8 q1 = *(const f16x8*)(qp + 16);

    // V gll source (per-lane): e-row vr = w*4 + (lane>>4) (+32 per round),
    // chunk pc = lane&15, source col pre-swizzled with the 4-bit involution:
    // n-chunk = pc ^ (vr & 15)
    const int vr = w * 4 + (lane >> 4);
    const half_t* vb = Vbg + (size_t)vr * Nn + (((lane & 15) ^ (vr & 15)) * 8);

    // PV V-read offsets: row el = et*32+l31 -> (el&15) = (l31&15); logical chunk
    // c = kk*4 + ks*2 + hi, physical = c ^ (l31 & 15)
    const int e15  = l31 & 15;
    const int off0 = (((kk * 4) + hi) ^ e15) * 8;
    const int off1 = (((kk * 4) + 2 + hi) ^ e15) * 8;

    f32x16 acc[8] = {};   // [et]: col e = et*32+l31, row m = mrow0+(r&3)+8*(r>>2)+4*hi
    float run_m = -1e30f, run_l = 0.f;
    const f32x16 zero16 = {};

    f32x16 s;             // current tile's S^T (log2 units)
    f16x8 kq0, kq1;       // K frags for NEXT tile

    // ---- prologue: QK(0) direct; gll V(0); prefetch K(1) ----
    {
        const half_t* kp0 = Kb + (size_t)(kk * 32 + l31) * PD + hi * 8;
        const f16x8 ka = *(const f16x8*)kp0;
        const f16x8 kb = *(const f16x8*)(kp0 + 16);
        s = __builtin_amdgcn_mfma_f32_32x32x16_f16(ka, q0, zero16, 0, 0, 0);
        s = __builtin_amdgcn_mfma_f32_32x32x16_f16(kb, q1, s, 0, 0, 0);
    }
#pragma unroll
    for (int rr = 0; rr < 8; ++rr)
        gll16(vb + (size_t)rr * 32 * Nn, &V_lds[0][rr * 4096 + w * 512]);
    __builtin_amdgcn_sched_barrier(0);
    const half_t* kp = Kb + (size_t)(128 + kk * 32 + l31) * PD + hi * 8;
    kq0 = *(const f16x8*)kp;
    kq1 = *(const f16x8*)(kp + 16);
    __builtin_amdgcn_sched_barrier(0);

    constexpr int NT = Nn / 128;
    for (int i = 0; i < NT; ++i) {
        const int buf = i & 1;
        const bool more = (i + 1 < NT);

        // counted drain: the 8 gll for tile i are the oldest; 2 K loads may stay.
        asm volatile("s_waitcnt vmcnt(2)" ::: "memory");
        __builtin_amdgcn_s_barrier();
        __builtin_amdgcn_sched_barrier(0);

        // ---- softmax in-register, log2-native (row m = l31) ----
        float tm = s[0];
#pragma unroll
        for (int r = 1; r < 16; ++r) tm = fmaxf(tm, s[r]);
        {
            const i32x2 rr = pl32swap(asi(tm), asi(tm));
            tm = fmaxf(asf(rr[0]), asf(rr[1]));
        }
        float alpha = 1.f;
        if (__any(tm > run_m + THR)) {
            const float nm = fmaxf(run_m, tm);
            alpha = __builtin_amdgcn_exp2f(run_m - nm);
            run_m = nm;
            float a16[16];
#pragma unroll
            for (int r = 0; r < 16; ++r)
                a16[r] = __shfl(alpha, (r & 3) + 8 * (r >> 2) + 4 * hi);
#pragma unroll
            for (int et = 0; et < 8; ++et)
#pragma unroll
                for (int r = 0; r < 16; ++r) acc[et][r] *= a16[r];
        }

        float p[16];
#pragma unroll
        for (int r = 0; r < 16; ++r)
            p[r] = __builtin_amdgcn_exp2f(s[r] - run_m);
        float rs = (((p[0] + p[1]) + (p[2] + p[3])) + ((p[4] + p[5]) + (p[6] + p[7])))
                 + (((p[8] + p[9]) + (p[10] + p[11])) + ((p[12] + p[13]) + (p[14] + p[15])));
        {
            const i32x2 rr = pl32swap(asi(rs), asi(rs));
            rs = asf(rr[0]) + asf(rr[1]);
        }
        run_l = run_l * alpha + rs;

        // ---- pack P into PV A-frags (v10-verified) ----
        f16x8 pa0, pa1;
        {
            const i32x2 r0 = pl32swap((int)pkrtz(p[0], p[1]), (int)pkrtz(p[4], p[5]));
            const i32x2 r1 = pl32swap((int)pkrtz(p[2], p[3]), (int)pkrtz(p[6], p[7]));
            u32x4 d0 = {(uint32_t)r0[0], (uint32_t)r1[0], (uint32_t)r0[1], (uint32_t)r1[1]};
            pa0 = __builtin_bit_cast(f16x8, d0);
            const i32x2 r2 = pl32swap((int)pkrtz(p[8], p[9]),   (int)pkrtz(p[12], p[13]));
            const i32x2 r3 = pl32swap((int)pkrtz(p[10], p[11]), (int)pkrtz(p[14], p[15]));
            u32x4 d1 = {(uint32_t)r2[0], (uint32_t)r3[0], (uint32_t)r2[1], (uint32_t)r3[1]};
            pa1 = __builtin_bit_cast(f16x8, d1);
        }

        // issue gll for tile i+1 into the other buffer
        if (more) {
#pragma unroll
            for (int rr = 0; rr < 8; ++rr)
                gll16(vb + 128 + (size_t)rr * 32 * Nn, &V_lds[buf ^ 1][rr * 4096 + w * 512]);
            vb += 128;
        }
        __builtin_amdgcn_sched_barrier(0);

        // ---- PV: 8 e-tiles x 2 k-steps over wave's 32n quarter ----
        __builtin_amdgcn_s_setprio(1);
#pragma unroll
        for (int et = 0; et < 8; ++et) {
            const int rowb = (et * 32 + l31) * 128;
            const f16x8 vf0 = *(const f16x8*)&V_lds[buf][rowb + off0];
            const f16x8 vf1 = *(const f16x8*)&V_lds[buf][rowb + off1];
            acc[et] = __builtin_amdgcn_mfma_f32_32x32x16_f16(pa0, vf0, acc[et], 0, 0, 0);
            acc[et] = __builtin_amdgcn_mfma_f32_32x32x16_f16(pa1, vf1, acc[et], 0, 0, 0);
        }
        __builtin_amdgcn_s_setprio(0);

        // ---- QK for tile i+1; prefetch K for i+2 (tail-wrapped) ----
        if (more) {
            s = __builtin_amdgcn_mfma_f32_32x32x16_f16(kq0, q0, zero16, 0, 0, 0);
            s = __builtin_amdgcn_mfma_f32_32x32x16_f16(kq1, q1, s, 0, 0, 0);
            kp += 128 * PD;
            if (i + 2 >= NT) kp = Kb + (size_t)(kk * 32 + l31) * PD + hi * 8;  // dummy
            kq0 = *(const f16x8*)kp;
            kq1 = *(const f16x8*)(kp + 16);
            __builtin_amdgcn_sched_barrier(0);
        }
    }

    // ---- epilogue: 4-way kk merge with exact exp2 correction (log2 units) ----
    if (lane < 32) { mx[mh][kk][l31] = run_m; lx[mh][kk][l31] = run_l; }
    __syncthreads();

    float sc16[16], li16[16];
    {
        const float m0 = mx[mh][0][l31], m1 = mx[mh][1][l31];
        const float m2 = mx[mh][2][l31], m3 = mx[mh][3][l31];
        const float M  = fmaxf(fmaxf(m0, m1), fmaxf(m2, m3));
        const float L  = lx[mh][0][l31] * __builtin_amdgcn_exp2f(m0 - M)
                       + lx[mh][1][l31] * __builtin_amdgcn_exp2f(m1 - M)
                       + lx[mh][2][l31] * __builtin_amdgcn_exp2f(m2 - M)
                       + lx[mh][3][l31] * __builtin_amdgcn_exp2f(m3 - M);
        const float ssf = __builtin_amdgcn_exp2f(run_m - M);
        const float inv = 1.0f / L;
#pragma unroll
        for (int r = 0; r < 16; ++r) {
            const int src = (r & 3) + 8 * (r >> 2) + 4 * hi;
            sc16[r] = __shfl(ssf, src);
            li16[r] = __shfl(inv, src);
        }
    }
    __syncthreads();   // all mx/lx reads done before mrg overwrites V_lds

    const float gm = gamma_p[0];
    float4* mrg = (float4*)&V_lds[0][0];   // [slot 0..31][q 0..3][lane 0..63]
#pragma unroll
    for (int h = 0; h < 2; ++h) {
#pragma unroll
        for (int j = 0; j < 4; ++j) {
            const int et = h * 4 + j;
#pragma unroll
            for (int q = 0; q < 4; ++q) {
                float4 v;
                v.x = acc[et][4 * q + 0] * sc16[4 * q + 0];
                v.y = acc[et][4 * q + 1] * sc16[4 * q + 1];
                v.z = acc[et][4 * q + 2] * sc16[4 * q + 2];
                v.w = acc[et][4 * q + 3] * sc16[4 * q + 3];
                mrg[((w * 4 + j) * 4 + q) * 64 + lane] = v;
            }
        }
        __syncthreads();
        {
            const int et = h * 4 + kk;
            const int e  = et * 32 + l31;
#pragma unroll
            for (int q = 0; q < 4; ++q) {
                float4 s0 = mrg[(((mh * 4 + 0) * 4 + kk) * 4 + q) * 64 + lane];
                float4 s1 = mrg[(((mh * 4 + 1) * 4 + kk) * 4 + q) * 64 + lane];
                float4 s2 = mrg[(((mh * 4 + 2) * 4 + kk) * 4 + q) * 64 + lane];
                float4 s3 = mrg[(((mh * 4 + 3) * 4 + kk) * 4 + q) * 64 + lane];
                const size_t idx = ((size_t)b * Cc + e) * Nn + mrow0 + 8 * q + 4 * hi;
                const float4 xin = *(const float4*)&x[idx];
                float4 o;
                o.x = gm * (s0.x + s1.x + s2.x + s3.x) * li16[4 * q + 0] + xin.x;
                o.y = gm * (s0.y + s1.y + s2.y + s3.y) * li16[4 * q + 1] + xin.y;
                o.z = gm * (s0.z + s1.z + s2.z + s3.z) * li16[4 * q + 2] + xin.z;
                o.w = gm * (s0.w + s1.w + s2.w + s3.w) * li16[4 * q + 3] + xin.w;
                *(float4*)&out[idx] = o;
            }
        }
        __syncthreads();
    }
}

extern "C" void kernel_launch(void* const* d_in, const int* in_sizes, int n_in,
                              void* d_out, int out_size, void* d_ws, size_t ws_size,
                              hipStream_t stream) {
    (void)in_sizes; (void)n_in; (void)out_size; (void)d_ws; (void)ws_size;
    const float* x  = (const float*)d_in[0];
    const float* Wq = (const float*)d_in[1];
    const float* bq = (const float*)d_in[2];
    const float* Wk = (const float*)d_in[3];
    const float* bk = (const float*)d_in[4];
    const float* Wv = (const float*)d_in[5];
    const float* bv = (const float*)d_in[6];
    const float* gm = (const float*)d_in[7];
    float* out = (float*)d_out;

    proj_kernel<<<512, 256, 0, stream>>>(x, Wq, bq, Wk, bk, Wv, bv);
    attn_kernel<<<256, 512, 0, stream>>>(x, gm, out);
}